// Round 1
// baseline (3434.564 us; speedup 1.0000x reference)
//
#include <hip/hip_runtime.h>
#include <hip/hip_bf16.h>
#include <math.h>

namespace {

constexpr int cE  = 512;    // embed dim
constexpr int cH  = 512;    // total hidden (2 dirs)
constexpr int cT  = 76;     // tags
constexpr int cB  = 256;    // batch
constexpr int cS  = 128;    // seq len
constexpr int cHD = 256;    // per-dir hidden
constexpr int cNG = 1024;   // 4*HD gate width
constexpr int cM  = cS * cB; // 32768 rows of (S,B) flattened

__device__ __forceinline__ float fsig(float x) { return 1.0f / (1.0f + __expf(-x)); }
__device__ __forceinline__ float ftanh_(float x) {
  // tanh(x) = sign(x) * (1 - 2/(e^{2|x|}+1)); robust for large |x| (inf -> 1)
  float e = __expf(2.0f * fabsf(x));
  float t = 1.0f - 2.0f / (e + 1.0f);
  return copysignf(t, x);
}
__device__ __forceinline__ unsigned short f2bf(float f) {
  __hip_bfloat16 h = __float2bfloat16(f);
  return *reinterpret_cast<unsigned short*>(&h);
}

// ---------------------------------------------------------------------------
// GEMM 1: P[m][n] = sum_k embed[ids(m)][k] * W[n][k] + b1[n] + b2[n]   (bf16 out)
// m = s*B + b ; ids(m) = input_ids[b*S + s]. M=32768, N=1024, K=512.
// 64x64 tile, K-tile 16, 4x4 micro per thread, 256 threads.
// ---------------------------------------------------------------------------
__global__ __launch_bounds__(256) void k_embed_gemm(
    const int* __restrict__ ids, const float* __restrict__ embed,
    const float* __restrict__ W, const float* __restrict__ b1,
    const float* __restrict__ b2, __hip_bfloat16* __restrict__ P)
{
  __shared__ float As[16][68];
  __shared__ float Bs[16][68];
  const int tid = threadIdx.x;
  const int tx = tid & 15, ty = tid >> 4;
  const int m0 = blockIdx.y * 64, n0 = blockIdx.x * 64;
  const int lm = tid >> 2;          // 0..63 row-in-tile loaded by this thread
  const int lk = (tid & 3) * 4;     // k offset 0,4,8,12
  const int m  = m0 + lm;
  const int gid = ids[(m & (cB - 1)) * cS + (m >> 8)];   // b*S + s
  const float* arow = embed + (size_t)gid * cE;
  const float* brow = W + (size_t)(n0 + lm) * cE;
  float acc[4][4] = {};
  for (int k0 = 0; k0 < cE; k0 += 16) {
    const float4 av = *(const float4*)(arow + k0 + lk);
    const float4 bv = *(const float4*)(brow + k0 + lk);
    __syncthreads();
    As[lk+0][lm]=av.x; As[lk+1][lm]=av.y; As[lk+2][lm]=av.z; As[lk+3][lm]=av.w;
    Bs[lk+0][lm]=bv.x; Bs[lk+1][lm]=bv.y; Bs[lk+2][lm]=bv.z; Bs[lk+3][lm]=bv.w;
    __syncthreads();
#pragma unroll
    for (int kk = 0; kk < 16; ++kk) {
      const float4 a4 = *(const float4*)(&As[kk][ty*4]);
      const float4 b4 = *(const float4*)(&Bs[kk][tx*4]);
      const float a[4] = {a4.x,a4.y,a4.z,a4.w};
      const float b[4] = {b4.x,b4.y,b4.z,b4.w};
#pragma unroll
      for (int i=0;i<4;++i)
#pragma unroll
        for (int j=0;j<4;++j) acc[i][j] += a[i]*b[j];
    }
  }
#pragma unroll
  for (int i=0;i<4;++i) {
    const int mrow = m0 + ty*4 + i;
    ushort4 u;
    unsigned short* up = &u.x;
#pragma unroll
    for (int j=0;j<4;++j) {
      const int n = n0 + tx*4 + j;
      up[j] = f2bf(acc[i][j] + b1[n] + b2[n]);
    }
    *reinterpret_cast<ushort4*>(P + (size_t)mrow * cNG + n0 + tx*4) = u;
  }
}

// ---------------------------------------------------------------------------
// GEMM 3: em[m][n] = sum_k feats[m][k] * W_out[n][k] + b_out[n]  (f32 out)
// M=32768, N=76 (guarded), K=512. Same tiling as above.
// ---------------------------------------------------------------------------
__global__ __launch_bounds__(256) void k_em_gemm(
    const float* __restrict__ A, const float* __restrict__ W,
    const float* __restrict__ bias, float* __restrict__ C)
{
  __shared__ float As[16][68];
  __shared__ float Bs[16][68];
  const int tid = threadIdx.x;
  const int tx = tid & 15, ty = tid >> 4;
  const int m0 = blockIdx.y * 64, n0 = blockIdx.x * 64;
  const int lm = tid >> 2;
  const int lk = (tid & 3) * 4;
  const float* arow = A + (size_t)(m0 + lm) * cH;
  const int nrow = n0 + lm;
  const bool bval = nrow < cT;
  const float* brow = W + (size_t)(bval ? nrow : 0) * cH;
  float acc[4][4] = {};
  for (int k0 = 0; k0 < cH; k0 += 16) {
    const float4 av = *(const float4*)(arow + k0 + lk);
    float4 bv = make_float4(0.f,0.f,0.f,0.f);
    if (bval) bv = *(const float4*)(brow + k0 + lk);
    __syncthreads();
    As[lk+0][lm]=av.x; As[lk+1][lm]=av.y; As[lk+2][lm]=av.z; As[lk+3][lm]=av.w;
    Bs[lk+0][lm]=bv.x; Bs[lk+1][lm]=bv.y; Bs[lk+2][lm]=bv.z; Bs[lk+3][lm]=bv.w;
    __syncthreads();
#pragma unroll
    for (int kk = 0; kk < 16; ++kk) {
      const float4 a4 = *(const float4*)(&As[kk][ty*4]);
      const float4 b4 = *(const float4*)(&Bs[kk][tx*4]);
      const float a[4] = {a4.x,a4.y,a4.z,a4.w};
      const float b[4] = {b4.x,b4.y,b4.z,b4.w};
#pragma unroll
      for (int i=0;i<4;++i)
#pragma unroll
        for (int j=0;j<4;++j) acc[i][j] += a[i]*b[j];
    }
  }
#pragma unroll
  for (int i=0;i<4;++i) {
    const int mrow = m0 + ty*4 + i;
#pragma unroll
    for (int j=0;j<4;++j) {
      const int n = n0 + tx*4 + j;
      if (n < cT) C[(size_t)mrow * cT + n] = acc[i][j] + bias[n];
    }
  }
}

// ---------------------------------------------------------------------------
// One LSTM time step, both directions (z=blockIdx.z). Computes
//   z = P[t] + h_prev @ W_hh^T ; gates ; c' ; h' -> feats[t][b][d*HD + j]
// h_prev is read from feats (t-1 fwd / t+1 bwd) or h0 at step 0.
// Block: 256 thr = 16(tx=j) x 16(ty=b-pair); tile 32b x 16j; per thread 2b x 1j x 4 gates.
// ---------------------------------------------------------------------------
__global__ __launch_bounds__(256) void k_lstm_step(
    int t_f, int t_b,
    const float* __restrict__ hinF, int strF,
    const float* __restrict__ hinB, int strB,
    const float* __restrict__ cinF, const float* __restrict__ cinB,
    float* __restrict__ coutF, float* __restrict__ coutB,
    const __hip_bfloat16* __restrict__ Pf, const __hip_bfloat16* __restrict__ Pb,
    const float* __restrict__ Wf, const float* __restrict__ Wb,
    float* __restrict__ feats)
{
  const int d  = blockIdx.z;
  const int j0 = blockIdx.x * 16;
  const int b0 = blockIdx.y * 32;
  const float* hin = d ? hinB : hinF;
  const int hstr   = d ? strB : strF;
  const float* cin = d ? cinB : cinF;
  float* cout      = d ? coutB : coutF;
  const __hip_bfloat16* P = d ? Pb : Pf;
  const float* W   = d ? Wb : Wf;
  const int t      = d ? t_b : t_f;

  __shared__ float hs[32][68];   // [b_local][k]
  __shared__ float ws[64][68];   // [g*16 + j_local][k]

  const int tid = threadIdx.x;
  const int tx = tid & 15;       // j_local
  const int ty = tid >> 4;       // b-pair index

  const int h_bb = tid >> 3;           // 0..31
  const int h_kb = (tid & 7) * 8;      // 0..56
  const int w_nv = tid >> 2;           // 0..63
  const int w_kb = (tid & 3) * 16;     // 0..48
  const int w_g  = w_nv >> 4;
  const int w_jl = w_nv & 15;
  const float* hrow = hin + (size_t)(b0 + h_bb) * hstr;
  const float* wrow = W + (size_t)(w_g * cHD + j0 + w_jl) * cHD;

  float acc[2][4] = {};

  for (int k0 = 0; k0 < cHD; k0 += 64) {
    const float4 hv0 = *(const float4*)(hrow + k0 + h_kb);
    const float4 hv1 = *(const float4*)(hrow + k0 + h_kb + 4);
    const float4 wv0 = *(const float4*)(wrow + k0 + w_kb);
    const float4 wv1 = *(const float4*)(wrow + k0 + w_kb + 4);
    const float4 wv2 = *(const float4*)(wrow + k0 + w_kb + 8);
    const float4 wv3 = *(const float4*)(wrow + k0 + w_kb + 12);
    __syncthreads();
    *(float4*)(&hs[h_bb][h_kb])     = hv0;
    *(float4*)(&hs[h_bb][h_kb + 4]) = hv1;
    *(float4*)(&ws[w_nv][w_kb])      = wv0;
    *(float4*)(&ws[w_nv][w_kb + 4])  = wv1;
    *(float4*)(&ws[w_nv][w_kb + 8])  = wv2;
    *(float4*)(&ws[w_nv][w_kb + 12]) = wv3;
    __syncthreads();
#pragma unroll
    for (int kk = 0; kk < 64; kk += 4) {
      const float4 h0v = *(const float4*)(&hs[ty*2 + 0][kk]);
      const float4 h1v = *(const float4*)(&hs[ty*2 + 1][kk]);
      const float hh[2][4] = {{h0v.x,h0v.y,h0v.z,h0v.w},{h1v.x,h1v.y,h1v.z,h1v.w}};
#pragma unroll
      for (int g = 0; g < 4; ++g) {
        const float4 wv = *(const float4*)(&ws[g*16 + tx][kk]);
        const float wa[4] = {wv.x,wv.y,wv.z,wv.w};
#pragma unroll
        for (int bi = 0; bi < 2; ++bi)
          acc[bi][g] += hh[bi][0]*wa[0] + hh[bi][1]*wa[1]
                      + hh[bi][2]*wa[2] + hh[bi][3]*wa[3];
      }
    }
  }

  const int j = j0 + tx;
#pragma unroll
  for (int bi = 0; bi < 2; ++bi) {
    const int b = b0 + ty*2 + bi;
    const size_t prow = ((size_t)t * cB + b) * cNG;
    const float zi = acc[bi][0] + __bfloat162float(P[prow + 0*cHD + j]);
    const float zf = acc[bi][1] + __bfloat162float(P[prow + 1*cHD + j]);
    const float zg = acc[bi][2] + __bfloat162float(P[prow + 2*cHD + j]);
    const float zo = acc[bi][3] + __bfloat162float(P[prow + 3*cHD + j]);
    const float ig = fsig(zi), fg = fsig(zf), gg = ftanh_(zg), og = fsig(zo);
    const float cc = fg * cin[b * cHD + j] + ig * gg;
    cout[b * cHD + j] = cc;
    feats[((size_t)t * cB + b) * cH + d * cHD + j] = og * ftanh_(cc);
  }
}

// ---------------------------------------------------------------------------
// CRF: one block per batch element. 128 threads.
//  - gold-path score: parallel over t (order-independent sum), block reduce
//  - forward algorithm: j = tid (<76), ping-pong alpha in LDS, loop to len-1
// ---------------------------------------------------------------------------
__global__ __launch_bounds__(128) void k_crf(
    const float* __restrict__ em,       // (S,B,T)
    const int* __restrict__ tag_ids,    // (B,S)
    const int* __restrict__ lengths,    // (B,)
    const float* __restrict__ start_trans,
    const float* __restrict__ end_trans,
    const float* __restrict__ trans,    // (T,T)
    float* __restrict__ llh)            // (B,)
{
  const int b = blockIdx.x;
  const int tid = threadIdx.x;
  const int len = lengths[b];

  __shared__ float trans_s[cT * cT];
  __shared__ float a0[80], a1[80];
  __shared__ float red[128];
  __shared__ float score_sh;

  for (int i = tid; i < cT * cT; i += 128) trans_s[i] = trans[i];
  __syncthreads();

  // ---- numerator (gold path score), t = tid (S == 128 == blockDim) ----
  float contrib = 0.f;
  {
    const int t = tid;
    if (t == 0) {
      const int tg = tag_ids[b * cS + 0];
      contrib += start_trans[tg] + em[(size_t)b * cT + tg];
    } else if (t < len) {
      const int tg = tag_ids[b * cS + t];
      const int tp = tag_ids[b * cS + t - 1];
      contrib += trans_s[tp * cT + tg] + em[((size_t)t * cB + b) * cT + tg];
    }
    if (t == len - 1) contrib += end_trans[tag_ids[b * cS + len - 1]];
  }
  red[tid] = contrib;
  __syncthreads();
  for (int s = 64; s > 0; s >>= 1) {
    if (tid < s) red[tid] += red[tid + s];
    __syncthreads();
  }
  if (tid == 0) score_sh = red[0];

  // ---- denominator: forward algorithm ----
  float* cur = a0;
  float* nxt = a1;
  if (tid < cT) cur[tid] = start_trans[tid] + em[(size_t)b * cT + tid];
  __syncthreads();
  for (int t = 1; t < len; ++t) {
    if (tid < cT) {
      float m = -1e30f;
      for (int i = 0; i < cT; ++i) m = fmaxf(m, cur[i] + trans_s[i * cT + tid]);
      float ss = 0.f;
      for (int i = 0; i < cT; ++i) ss += __expf(cur[i] + trans_s[i * cT + tid] - m);
      nxt[tid] = m + __logf(ss) + em[((size_t)t * cB + b) * cT + tid];
    }
    __syncthreads();
    float* tmp = cur; cur = nxt; nxt = tmp;
  }

  // logZ = logsumexp_j(cur[j] + end_trans[j])
  const float v = (tid < cT) ? cur[tid] + end_trans[tid] : -1e30f;
  __syncthreads();
  red[tid] = v;
  __syncthreads();
  for (int s = 64; s > 0; s >>= 1) {
    if (tid < s) red[tid] = fmaxf(red[tid], red[tid + s]);
    __syncthreads();
  }
  const float mx = red[0];
  __syncthreads();
  red[tid] = (tid < cT) ? __expf(v - mx) : 0.f;
  __syncthreads();
  for (int s = 64; s > 0; s >>= 1) {
    if (tid < s) red[tid] += red[tid + s];
    __syncthreads();
  }
  if (tid == 0) llh[b] = score_sh - (mx + __logf(red[0]));
}

__global__ __launch_bounds__(256) void k_final(const float* __restrict__ llh,
                                               float* __restrict__ out)
{
  __shared__ float red[256];
  const int tid = threadIdx.x;
  red[tid] = llh[tid];
  __syncthreads();
  for (int s = 128; s > 0; s >>= 1) {
    if (tid < s) red[tid] += red[tid + s];
    __syncthreads();
  }
  if (tid == 0) out[0] = -red[0] * (1.0f / cB);
}

} // anonymous namespace

extern "C" void kernel_launch(void* const* d_in, const int* in_sizes, int n_in,
                              void* d_out, int out_size, void* d_ws, size_t ws_size,
                              hipStream_t stream) {
  const int*   input_ids   = (const int*)  d_in[0];
  const int*   tag_ids     = (const int*)  d_in[1];
  const int*   lengths     = (const int*)  d_in[2];
  const float* embed_table = (const float*)d_in[3];
  const float* W_ih_f      = (const float*)d_in[4];
  const float* W_hh_f      = (const float*)d_in[5];
  const float* b_ih_f      = (const float*)d_in[6];
  const float* b_hh_f      = (const float*)d_in[7];
  const float* W_ih_b      = (const float*)d_in[8];
  const float* W_hh_b      = (const float*)d_in[9];
  const float* b_ih_b      = (const float*)d_in[10];
  const float* b_hh_b      = (const float*)d_in[11];
  const float* W_out       = (const float*)d_in[12];
  const float* b_out       = (const float*)d_in[13];
  const float* start_trans = (const float*)d_in[14];
  const float* end_trans   = (const float*)d_in[15];
  const float* trans       = (const float*)d_in[16];
  const float* h0          = (const float*)d_in[17];
  const float* c0          = (const float*)d_in[18];
  float* out = (float*)d_out;

  // workspace layout
  char* wsb = (char*)d_ws;
  const size_t szP     = (size_t)cM * cNG * sizeof(__hip_bfloat16); // 64 MiB
  const size_t szFeats = (size_t)cM * cH * sizeof(float);           // 64 MiB
  const size_t szEm    = (size_t)cM * cT * sizeof(float);           // ~9.5 MiB
  const size_t szC     = (size_t)cB * cHD * sizeof(float);          // 256 KiB
  __hip_bfloat16* Pf = (__hip_bfloat16*)(wsb);
  __hip_bfloat16* Pb = (__hip_bfloat16*)(wsb + szP);
  float* feats = (float*)(wsb + 2*szP);
  float* em    = (float*)(wsb + 2*szP + szFeats);
  float* c_f   = (float*)(wsb + 2*szP + szFeats + szEm);
  float* c_b   = (float*)(wsb + 2*szP + szFeats + szEm + szC);
  float* llh   = (float*)(wsb + 2*szP + szFeats + szEm + 2*szC);

  // 1) input projections (gather fused), both directions
  dim3 g1(cNG / 64, cM / 64);   // (16, 512)
  k_embed_gemm<<<g1, 256, 0, stream>>>(input_ids, embed_table, W_ih_f, b_ih_f, b_hh_f, Pf);
  k_embed_gemm<<<g1, 256, 0, stream>>>(input_ids, embed_table, W_ih_b, b_ih_b, b_hh_b, Pb);

  // 2) recurrence: 128 steps, both directions per launch
  dim3 g2(cHD / 16, cB / 32, 2); // (16, 8, 2) = 256 blocks
  for (int tau = 0; tau < cS; ++tau) {
    const int t_f = tau;
    const int t_b = cS - 1 - tau;
    const float *hinF, *hinB, *cinF, *cinB;
    int strF, strB;
    if (tau == 0) {
      hinF = h0;                strF = cHD;
      hinB = h0 + (size_t)cB * cHD; strB = cHD;
      cinF = c0;
      cinB = c0 + (size_t)cB * cHD;
    } else {
      hinF = feats + (size_t)(t_f - 1) * cB * cH;        strF = cH;
      hinB = feats + (size_t)(t_b + 1) * cB * cH + cHD;  strB = cH;
      cinF = c_f;
      cinB = c_b;
    }
    k_lstm_step<<<g2, 256, 0, stream>>>(t_f, t_b, hinF, strF, hinB, strB,
                                        cinF, cinB, c_f, c_b,
                                        Pf, Pb, W_hh_f, W_hh_b, feats);
  }

  // 3) emissions
  dim3 g3((cT + 63) / 64, cM / 64);  // (2, 512)
  k_em_gemm<<<g3, 256, 0, stream>>>(feats, W_out, b_out, em);

  // 4) CRF per batch element + final mean
  k_crf<<<cB, 128, 0, stream>>>(em, tag_ids, lengths, start_trans, end_trans, trans, llh);
  k_final<<<1, 256, 0, stream>>>(llh, out);
}

// Round 2
// 2103.659 us; speedup vs baseline: 1.6327x; 1.6327x over previous
//
#include <hip/hip_runtime.h>
#include <hip/hip_bf16.h>
#include <math.h>

namespace {

constexpr int cE  = 512;    // embed dim
constexpr int cH  = 512;    // total hidden (2 dirs)
constexpr int cT  = 76;     // tags
constexpr int cB  = 256;    // batch
constexpr int cS  = 128;    // seq len
constexpr int cHD = 256;    // per-dir hidden
constexpr int cNG = 1024;   // 4*HD gate width
constexpr int cM  = cS * cB; // 32768 rows of (S,B) flattened

typedef __attribute__((ext_vector_type(8))) short bf16x8;
typedef __attribute__((ext_vector_type(4))) float f32x4;

__device__ __forceinline__ float fsig(float x) { return 1.0f / (1.0f + __expf(-x)); }
__device__ __forceinline__ float ftanh_(float x) {
  float e = __expf(2.0f * fabsf(x));
  float t = 1.0f - 2.0f / (e + 1.0f);
  return copysignf(t, x);
}
__device__ __forceinline__ unsigned short f2bf(float f) {
  __hip_bfloat16 h = __float2bfloat16(f);
  return *reinterpret_cast<unsigned short*>(&h);
}
__device__ __forceinline__ unsigned int pack2bf(float a, float b) {
  return (unsigned int)f2bf(a) | ((unsigned int)f2bf(b) << 16);
}

// ---------------------------------------------------------------------------
// MFMA embed projection: P[m][n] = sum_k embed[ids(m)][k]*W[n][k] + b1[n]+b2[n]
// bf16 MFMA 16x16x32, tile 128m x 128n, BK=64 (2 k-slabs of 32), 4 waves.
// On-the-fly f32->bf16 cast during LDS staging. z = direction.
// LDS A/B layout: [kslab][row][32 bf16]; frag read = row (lane&15), 16B at quad.
// ---------------------------------------------------------------------------
__global__ __launch_bounds__(256) void k_embed_mfma(
    const int* __restrict__ ids, const float* __restrict__ embed,
    const float* __restrict__ Wf, const float* __restrict__ Wb,
    const float* __restrict__ b1f, const float* __restrict__ b2f,
    const float* __restrict__ b1b, const float* __restrict__ b2b,
    __hip_bfloat16* __restrict__ Pf, __hip_bfloat16* __restrict__ Pb)
{
  const int d = blockIdx.z;
  const float* W  = d ? Wb : Wf;
  const float* b1 = d ? b1b : b1f;
  const float* b2 = d ? b2b : b2f;
  unsigned short* P = (unsigned short*)(d ? Pb : Pf);

  const int n0 = blockIdx.x * 128;
  const int m0 = blockIdx.y * 128;
  const int tid = threadIdx.x;

  __shared__ unsigned short Al[2 * 128 * 32];
  __shared__ unsigned short Bl[2 * 128 * 32];
  __shared__ float bias_s[128];

  if (tid < 128) bias_s[tid] = b1[n0 + tid] + b2[n0 + tid];

  const int row  = tid >> 1;
  const int half = tid & 1;
  const int m  = m0 + row;
  const int id = ids[(m & (cB - 1)) * cS + (m >> 8)];
  const float* arow = embed + (size_t)id * cE + half * 32;
  const float* brow = W + (size_t)(n0 + row) * cE + half * 32;
  unsigned short* adst = &Al[half * 4096 + row * 32];
  unsigned short* bdst = &Bl[half * 4096 + row * 32];

  const int lane = tid & 63, wave = tid >> 6;
  const int wm = wave >> 1, wn = wave & 1;
  const int fr = lane & 15, fq = lane >> 4;

  f32x4 acc[4][4];
#pragma unroll
  for (int i = 0; i < 4; ++i)
#pragma unroll
    for (int j = 0; j < 4; ++j) acc[i][j] = (f32x4){0.f, 0.f, 0.f, 0.f};

  for (int kt = 0; kt < cE / 64; ++kt) {
    float4 av[8], bv[8];
    const float* ap = arow + kt * 64;
    const float* bp = brow + kt * 64;
#pragma unroll
    for (int q = 0; q < 8; ++q) {
      av[q] = *(const float4*)(ap + 4 * q);
      bv[q] = *(const float4*)(bp + 4 * q);
    }
    unsigned int pa[16], pb[16];
#pragma unroll
    for (int q = 0; q < 8; ++q) {
      pa[2*q]   = pack2bf(av[q].x, av[q].y);
      pa[2*q+1] = pack2bf(av[q].z, av[q].w);
      pb[2*q]   = pack2bf(bv[q].x, bv[q].y);
      pb[2*q+1] = pack2bf(bv[q].z, bv[q].w);
    }
    __syncthreads();   // prior mfma reads done before overwrite
#pragma unroll
    for (int q = 0; q < 4; ++q) {
      *(uint4*)(adst + q * 8) = make_uint4(pa[4*q], pa[4*q+1], pa[4*q+2], pa[4*q+3]);
      *(uint4*)(bdst + q * 8) = make_uint4(pb[4*q], pb[4*q+1], pb[4*q+2], pb[4*q+3]);
    }
    __syncthreads();
#pragma unroll
    for (int ks = 0; ks < 2; ++ks) {
      bf16x8 aF[4], bF[4];
#pragma unroll
      for (int i = 0; i < 4; ++i)
        aF[i] = *(const bf16x8*)(&Al[ks * 4096 + (wm * 64 + i * 16 + fr) * 32 + fq * 8]);
#pragma unroll
      for (int j = 0; j < 4; ++j)
        bF[j] = *(const bf16x8*)(&Bl[ks * 4096 + (wn * 64 + j * 16 + fr) * 32 + fq * 8]);
#pragma unroll
      for (int i = 0; i < 4; ++i)
#pragma unroll
        for (int j = 0; j < 4; ++j)
          acc[i][j] = __builtin_amdgcn_mfma_f32_16x16x32_bf16(aF[i], bF[j], acc[i][j], 0, 0, 0);
    }
  }

#pragma unroll
  for (int i = 0; i < 4; ++i)
#pragma unroll
    for (int j = 0; j < 4; ++j) {
      const int gcol = wn * 64 + j * 16 + fr;
#pragma unroll
      for (int r = 0; r < 4; ++r) {
        const int grow = m0 + wm * 64 + i * 16 + fq * 4 + r;
        P[(size_t)grow * cNG + n0 + gcol] = f2bf(acc[i][j][r] + bias_s[gcol]);
      }
    }
}

// ---------------------------------------------------------------------------
// GEMM 3: em[m][n] = sum_k feats[m][k] * W_out[n][k] + b_out[n]  (f32 out)
// ---------------------------------------------------------------------------
__global__ __launch_bounds__(256) void k_em_gemm(
    const float* __restrict__ A, const float* __restrict__ W,
    const float* __restrict__ bias, float* __restrict__ C)
{
  __shared__ float As[16][68];
  __shared__ float Bs[16][68];
  const int tid = threadIdx.x;
  const int tx = tid & 15, ty = tid >> 4;
  const int m0 = blockIdx.y * 64, n0 = blockIdx.x * 64;
  const int lm = tid >> 2;
  const int lk = (tid & 3) * 4;
  const float* arow = A + (size_t)(m0 + lm) * cH;
  const int nrow = n0 + lm;
  const bool bval = nrow < cT;
  const float* brow = W + (size_t)(bval ? nrow : 0) * cH;
  float acc[4][4] = {};
  for (int k0 = 0; k0 < cH; k0 += 16) {
    const float4 av = *(const float4*)(arow + k0 + lk);
    float4 bv = make_float4(0.f,0.f,0.f,0.f);
    if (bval) bv = *(const float4*)(brow + k0 + lk);
    __syncthreads();
    As[lk+0][lm]=av.x; As[lk+1][lm]=av.y; As[lk+2][lm]=av.z; As[lk+3][lm]=av.w;
    Bs[lk+0][lm]=bv.x; Bs[lk+1][lm]=bv.y; Bs[lk+2][lm]=bv.z; Bs[lk+3][lm]=bv.w;
    __syncthreads();
#pragma unroll
    for (int kk = 0; kk < 16; ++kk) {
      const float4 a4 = *(const float4*)(&As[kk][ty*4]);
      const float4 b4 = *(const float4*)(&Bs[kk][tx*4]);
      const float a[4] = {a4.x,a4.y,a4.z,a4.w};
      const float b[4] = {b4.x,b4.y,b4.z,b4.w};
#pragma unroll
      for (int i=0;i<4;++i)
#pragma unroll
        for (int j=0;j<4;++j) acc[i][j] += a[i]*b[j];
    }
  }
#pragma unroll
  for (int i=0;i<4;++i) {
    const int mrow = m0 + ty*4 + i;
#pragma unroll
    for (int j=0;j<4;++j) {
      const int n = n0 + tx*4 + j;
      if (n < cT) C[(size_t)mrow * cT + n] = acc[i][j] + bias[n];
    }
  }
}

// ---------------------------------------------------------------------------
// One LSTM time step, both directions (z=blockIdx.z).  (unchanged round 0)
// ---------------------------------------------------------------------------
__global__ __launch_bounds__(256) void k_lstm_step(
    int t_f, int t_b,
    const float* __restrict__ hinF, int strF,
    const float* __restrict__ hinB, int strB,
    const float* __restrict__ cinF, const float* __restrict__ cinB,
    float* __restrict__ coutF, float* __restrict__ coutB,
    const __hip_bfloat16* __restrict__ Pf, const __hip_bfloat16* __restrict__ Pb,
    const float* __restrict__ Wf, const float* __restrict__ Wb,
    float* __restrict__ feats)
{
  const int d  = blockIdx.z;
  const int j0 = blockIdx.x * 16;
  const int b0 = blockIdx.y * 32;
  const float* hin = d ? hinB : hinF;
  const int hstr   = d ? strB : strF;
  const float* cin = d ? cinB : cinF;
  float* cout      = d ? coutB : coutF;
  const __hip_bfloat16* P = d ? Pb : Pf;
  const float* W   = d ? Wb : Wf;
  const int t      = d ? t_b : t_f;

  __shared__ float hs[32][68];
  __shared__ float ws[64][68];

  const int tid = threadIdx.x;
  const int tx = tid & 15;
  const int ty = tid >> 4;

  const int h_bb = tid >> 3;
  const int h_kb = (tid & 7) * 8;
  const int w_nv = tid >> 2;
  const int w_kb = (tid & 3) * 16;
  const int w_g  = w_nv >> 4;
  const int w_jl = w_nv & 15;
  const float* hrow = hin + (size_t)(b0 + h_bb) * hstr;
  const float* wrow = W + (size_t)(w_g * cHD + j0 + w_jl) * cHD;

  float acc[2][4] = {};

  for (int k0 = 0; k0 < cHD; k0 += 64) {
    const float4 hv0 = *(const float4*)(hrow + k0 + h_kb);
    const float4 hv1 = *(const float4*)(hrow + k0 + h_kb + 4);
    const float4 wv0 = *(const float4*)(wrow + k0 + w_kb);
    const float4 wv1 = *(const float4*)(wrow + k0 + w_kb + 4);
    const float4 wv2 = *(const float4*)(wrow + k0 + w_kb + 8);
    const float4 wv3 = *(const float4*)(wrow + k0 + w_kb + 12);
    __syncthreads();
    *(float4*)(&hs[h_bb][h_kb])     = hv0;
    *(float4*)(&hs[h_bb][h_kb + 4]) = hv1;
    *(float4*)(&ws[w_nv][w_kb])      = wv0;
    *(float4*)(&ws[w_nv][w_kb + 4])  = wv1;
    *(float4*)(&ws[w_nv][w_kb + 8])  = wv2;
    *(float4*)(&ws[w_nv][w_kb + 12]) = wv3;
    __syncthreads();
#pragma unroll
    for (int kk = 0; kk < 64; kk += 4) {
      const float4 h0v = *(const float4*)(&hs[ty*2 + 0][kk]);
      const float4 h1v = *(const float4*)(&hs[ty*2 + 1][kk]);
      const float hh[2][4] = {{h0v.x,h0v.y,h0v.z,h0v.w},{h1v.x,h1v.y,h1v.z,h1v.w}};
#pragma unroll
      for (int g = 0; g < 4; ++g) {
        const float4 wv = *(const float4*)(&ws[g*16 + tx][kk]);
        const float wa[4] = {wv.x,wv.y,wv.z,wv.w};
#pragma unroll
        for (int bi = 0; bi < 2; ++bi)
          acc[bi][g] += hh[bi][0]*wa[0] + hh[bi][1]*wa[1]
                      + hh[bi][2]*wa[2] + hh[bi][3]*wa[3];
      }
    }
  }

  const int j = j0 + tx;
#pragma unroll
  for (int bi = 0; bi < 2; ++bi) {
    const int b = b0 + ty*2 + bi;
    const size_t prow = ((size_t)t * cB + b) * cNG;
    const float zi = acc[bi][0] + __bfloat162float(P[prow + 0*cHD + j]);
    const float zf = acc[bi][1] + __bfloat162float(P[prow + 1*cHD + j]);
    const float zg = acc[bi][2] + __bfloat162float(P[prow + 2*cHD + j]);
    const float zo = acc[bi][3] + __bfloat162float(P[prow + 3*cHD + j]);
    const float ig = fsig(zi), fg = fsig(zf), gg = ftanh_(zg), og = fsig(zo);
    const float cc = fg * cin[b * cHD + j] + ig * gg;
    cout[b * cHD + j] = cc;
    feats[((size_t)t * cB + b) * cH + d * cHD + j] = og * ftanh_(cc);
  }
}

// ---------------------------------------------------------------------------
// CRF: one block per batch element, 320 threads (5 waves).
//  - trans transposed into LDS, stride 81 (conflict-free); em[:,b,:] in LDS
//  - forward: j = tid>>2, 4 lanes split i in 19-chunks; shfl_xor combine.
//    Offset m = cur[0] (alpha spread bounded; no per-j max pass needed).
// ---------------------------------------------------------------------------
__global__ __launch_bounds__(320) void k_crf(
    const float* __restrict__ em,       // (S,B,T)
    const int* __restrict__ tag_ids,    // (B,S)
    const int* __restrict__ lengths,    // (B,)
    const float* __restrict__ start_trans,
    const float* __restrict__ end_trans,
    const float* __restrict__ trans,    // (T,T)
    float* __restrict__ llh)            // (B,)
{
  const int b = blockIdx.x;
  const int tid = threadIdx.x;
  const int len = lengths[b];

  __shared__ float trans_t[80 * 81];    // [j][i], stride 81
  __shared__ float em_s[cS * 80];       // [t][j], stride 80
  __shared__ float a0[80], a1[80];
  __shared__ float red[128];
  __shared__ float score_sh;

  for (int idx = tid; idx < cT * cT; idx += 320) {
    const int i = idx / cT, jj = idx - i * cT;
    trans_t[jj * 81 + i] = trans[idx];
  }
  for (int idx = tid; idx < cS * cT; idx += 320) {
    const int t = idx / cT, jj = idx - t * cT;
    em_s[t * 80 + jj] = em[((size_t)t * cB + b) * cT + jj];
  }
  __syncthreads();

  // ---- numerator (gold path score), t = tid, order-independent sum ----
  float contrib = 0.f;
  if (tid < cS) {
    const int t = tid;
    if (t == 0) {
      const int tg = tag_ids[b * cS];
      contrib = start_trans[tg] + em_s[tg];
    } else if (t < len) {
      const int tg = tag_ids[b * cS + t];
      const int tp = tag_ids[b * cS + t - 1];
      contrib = trans_t[tg * 81 + tp] + em_s[t * 80 + tg];
    }
    if (t == len - 1) contrib += end_trans[tag_ids[b * cS + len - 1]];
  }
  if (tid < 128) red[tid] = contrib;
  __syncthreads();
  for (int s = 64; s > 0; s >>= 1) {
    if (tid < s) red[tid] += red[tid + s];
    __syncthreads();
  }
  if (tid == 0) score_sh = red[0];

  // ---- denominator: forward algorithm ----
  const int j   = tid >> 2;
  const int sub = tid & 3;
  const int i0  = sub * 19;
  float* cur = a0;
  float* nxt = a1;
  if (sub == 0 && j < cT) cur[j] = start_trans[j] + em_s[j];
  __syncthreads();
  for (int t = 1; t < len; ++t) {
    const float mref = cur[0];
    const float* trow = &trans_t[j * 81 + i0];
    const float* crow = &cur[i0];
    float s = 0.f;
#pragma unroll
    for (int q = 0; q < 19; ++q)
      s += __expf(crow[q] + trow[q] - mref);
    s += __shfl_xor(s, 1);
    s += __shfl_xor(s, 2);
    if (sub == 0 && j < cT) nxt[j] = mref + __logf(s) + em_s[t * 80 + j];
    __syncthreads();
    float* tp2 = cur; cur = nxt; nxt = tp2;
  }

  // logZ = logsumexp_j(cur[j] + end_trans[j])
  const float v = (tid < cT) ? cur[tid] + end_trans[tid] : -1e30f;
  if (tid < 128) red[tid] = v;
  __syncthreads();
  for (int s = 64; s > 0; s >>= 1) {
    if (tid < s) red[tid] = fmaxf(red[tid], red[tid + s]);
    __syncthreads();
  }
  const float mx = red[0];
  __syncthreads();
  if (tid < 128) red[tid] = (tid < cT) ? __expf(v - mx) : 0.f;
  __syncthreads();
  for (int s = 64; s > 0; s >>= 1) {
    if (tid < s) red[tid] += red[tid + s];
    __syncthreads();
  }
  if (tid == 0) llh[b] = score_sh - (mx + __logf(red[0]));
}

__global__ __launch_bounds__(256) void k_final(const float* __restrict__ llh,
                                               float* __restrict__ out)
{
  __shared__ float red[256];
  const int tid = threadIdx.x;
  red[tid] = llh[tid];
  __syncthreads();
  for (int s = 128; s > 0; s >>= 1) {
    if (tid < s) red[tid] += red[tid + s];
    __syncthreads();
  }
  if (tid == 0) out[0] = -red[0] * (1.0f / cB);
}

} // anonymous namespace

extern "C" void kernel_launch(void* const* d_in, const int* in_sizes, int n_in,
                              void* d_out, int out_size, void* d_ws, size_t ws_size,
                              hipStream_t stream) {
  const int*   input_ids   = (const int*)  d_in[0];
  const int*   tag_ids     = (const int*)  d_in[1];
  const int*   lengths     = (const int*)  d_in[2];
  const float* embed_table = (const float*)d_in[3];
  const float* W_ih_f      = (const float*)d_in[4];
  const float* W_hh_f      = (const float*)d_in[5];
  const float* b_ih_f      = (const float*)d_in[6];
  const float* b_hh_f      = (const float*)d_in[7];
  const float* W_ih_b      = (const float*)d_in[8];
  const float* W_hh_b      = (const float*)d_in[9];
  const float* b_ih_b      = (const float*)d_in[10];
  const float* b_hh_b      = (const float*)d_in[11];
  const float* W_out       = (const float*)d_in[12];
  const float* b_out       = (const float*)d_in[13];
  const float* start_trans = (const float*)d_in[14];
  const float* end_trans   = (const float*)d_in[15];
  const float* trans       = (const float*)d_in[16];
  const float* h0          = (const float*)d_in[17];
  const float* c0          = (const float*)d_in[18];
  float* out = (float*)d_out;

  // workspace layout (unchanged from round 0)
  char* wsb = (char*)d_ws;
  const size_t szP     = (size_t)cM * cNG * sizeof(__hip_bfloat16);
  const size_t szFeats = (size_t)cM * cH * sizeof(float);
  const size_t szEm    = (size_t)cM * cT * sizeof(float);
  const size_t szC     = (size_t)cB * cHD * sizeof(float);
  __hip_bfloat16* Pf = (__hip_bfloat16*)(wsb);
  __hip_bfloat16* Pb = (__hip_bfloat16*)(wsb + szP);
  float* feats = (float*)(wsb + 2*szP);
  float* em    = (float*)(wsb + 2*szP + szFeats);
  float* c_f   = (float*)(wsb + 2*szP + szFeats + szEm);
  float* c_b   = (float*)(wsb + 2*szP + szFeats + szEm + szC);
  float* llh   = (float*)(wsb + 2*szP + szFeats + szEm + 2*szC);

  // 1) input projections, both directions, bf16 MFMA
  dim3 g1(cNG / 128, cM / 128, 2);   // (8, 256, 2)
  k_embed_mfma<<<g1, 256, 0, stream>>>(input_ids, embed_table,
                                       W_ih_f, W_ih_b,
                                       b_ih_f, b_hh_f, b_ih_b, b_hh_b,
                                       Pf, Pb);

  // 2) recurrence: 128 steps, both directions per launch
  dim3 g2(cHD / 16, cB / 32, 2); // (16, 8, 2) = 256 blocks
  for (int tau = 0; tau < cS; ++tau) {
    const int t_f = tau;
    const int t_b = cS - 1 - tau;
    const float *hinF, *hinB, *cinF, *cinB;
    int strF, strB;
    if (tau == 0) {
      hinF = h0;                strF = cHD;
      hinB = h0 + (size_t)cB * cHD; strB = cHD;
      cinF = c0;
      cinB = c0 + (size_t)cB * cHD;
    } else {
      hinF = feats + (size_t)(t_f - 1) * cB * cH;        strF = cH;
      hinB = feats + (size_t)(t_b + 1) * cB * cH + cHD;  strB = cH;
      cinF = c_f;
      cinB = c_b;
    }
    k_lstm_step<<<g2, 256, 0, stream>>>(t_f, t_b, hinF, strF, hinB, strB,
                                        cinF, cinB, c_f, c_b,
                                        Pf, Pb, W_hh_f, W_hh_b, feats);
  }

  // 3) emissions
  dim3 g3((cT + 63) / 64, cM / 64);  // (2, 512)
  k_em_gemm<<<g3, 256, 0, stream>>>(feats, W_out, b_out, em);

  // 4) CRF per batch element + final mean
  k_crf<<<cB, 320, 0, stream>>>(em, tag_ids, lengths, start_trans, end_trans, trans, llh);
  k_final<<<1, 256, 0, stream>>>(llh, out);
}

// Round 3
// 1351.396 us; speedup vs baseline: 2.5415x; 1.5567x over previous
//
#include <hip/hip_runtime.h>
#include <hip/hip_bf16.h>
#include <math.h>

namespace {

constexpr int cE  = 512;    // embed dim
constexpr int cH  = 512;    // total hidden (2 dirs)
constexpr int cT  = 76;     // tags
constexpr int cB  = 256;    // batch
constexpr int cS  = 128;    // seq len
constexpr int cHD = 256;    // per-dir hidden
constexpr int cNG = 1024;   // 4*HD gate width
constexpr int cM  = cS * cB; // 32768 rows of (S,B) flattened

typedef __attribute__((ext_vector_type(8))) short bf16x8;
typedef __attribute__((ext_vector_type(4))) float f32x4;

__device__ __forceinline__ float fsig(float x) { return 1.0f / (1.0f + __expf(-x)); }
__device__ __forceinline__ float ftanh_(float x) {
  float e = __expf(2.0f * fabsf(x));
  float t = 1.0f - 2.0f / (e + 1.0f);
  return copysignf(t, x);
}
__device__ __forceinline__ unsigned short f2bf(float f) {
  __hip_bfloat16 h = __float2bfloat16(f);
  return *reinterpret_cast<unsigned short*>(&h);
}
__device__ __forceinline__ unsigned int pack2bf(float a, float b) {
  return (unsigned int)f2bf(a) | ((unsigned int)f2bf(b) << 16);
}
__device__ __forceinline__ float bf2f(unsigned short u) {
  unsigned int v = ((unsigned int)u) << 16;
  return *reinterpret_cast<float*>(&v);
}

// ---------------------------------------------------------------------------
// Prep: W_hh (both dirs) -> bf16 [d][1024][256]; h0 -> bf16 ping buffer;
// c0 -> f32 working copy.
// ---------------------------------------------------------------------------
__global__ __launch_bounds__(256) void k_prep(
    const float* __restrict__ Wf, const float* __restrict__ Wb,
    const float* __restrict__ h0, const float* __restrict__ c0,
    unsigned short* __restrict__ Wbf, unsigned short* __restrict__ hA,
    float* __restrict__ cbuf)
{
  const int i = blockIdx.x * 256 + threadIdx.x;
  const int nWhalf = 1024 * 256;
  if (i < 2 * nWhalf) {
    const float v = (i < nWhalf) ? Wf[i] : Wb[i - nWhalf];
    Wbf[i] = f2bf(v);
  }
  if (i < 2 * cB * cHD) {
    hA[i] = f2bf(h0[i]);
    cbuf[i] = c0[i];
  }
}

// ---------------------------------------------------------------------------
// MFMA embed projection: P[m][n] = sum_k embed[ids(m)][k]*W[n][k] + b1[n]+b2[n]
// 1D grid 4096, XCD-aware remap: xcd=bid&7 owns m-tiles [xcd*32,xcd*32+32);
// consecutive blocks on one XCD sweep all 16 (n,d) of one m-tile (A reuse).
// LDS row stride 40 shorts (80 B) -> bank-start period 8 covers all 32 banks
// -> conflict-free b128 staging writes and fragment reads.
// ---------------------------------------------------------------------------
__global__ __launch_bounds__(256) void k_embed_mfma(
    const int* __restrict__ ids, const float* __restrict__ embed,
    const float* __restrict__ Wf, const float* __restrict__ Wb,
    const float* __restrict__ b1f, const float* __restrict__ b2f,
    const float* __restrict__ b1b, const float* __restrict__ b2b,
    __hip_bfloat16* __restrict__ Pf, __hip_bfloat16* __restrict__ Pb)
{
  const int bid = blockIdx.x;
  const int xcd = bid & 7;
  const int jj  = bid >> 3;          // 0..511
  const int m_tile = xcd * 32 + (jj >> 4);
  const int nz  = jj & 15;
  const int n_tile = nz & 7;
  const int d   = nz >> 3;

  const float* W  = d ? Wb : Wf;
  const float* b1 = d ? b1b : b1f;
  const float* b2 = d ? b2b : b2f;
  unsigned short* P = (unsigned short*)(d ? Pb : Pf);

  const int n0 = n_tile * 128;
  const int m0 = m_tile * 128;
  const int tid = threadIdx.x;

  constexpr int RS = 40;              // row stride in shorts (80 B)
  constexpr int SLAB = 128 * RS;      // shorts per k-slab
  __shared__ unsigned short Al[2 * SLAB];
  __shared__ unsigned short Bl[2 * SLAB];
  __shared__ float bias_s[128];

  if (tid < 128) bias_s[tid] = b1[n0 + tid] + b2[n0 + tid];

  const int row  = tid >> 1;
  const int half = tid & 1;
  const int m  = m0 + row;
  const int id = ids[(m & (cB - 1)) * cS + (m >> 8)];
  const float* arow = embed + (size_t)id * cE + half * 32;
  const float* brow = W + (size_t)(n0 + row) * cE + half * 32;
  unsigned short* adst = &Al[half * SLAB + row * RS];
  unsigned short* bdst = &Bl[half * SLAB + row * RS];

  const int lane = tid & 63, wave = tid >> 6;
  const int wm = wave >> 1, wn = wave & 1;
  const int fr = lane & 15, fq = lane >> 4;

  f32x4 acc[4][4];
#pragma unroll
  for (int i = 0; i < 4; ++i)
#pragma unroll
    for (int j = 0; j < 4; ++j) acc[i][j] = (f32x4){0.f, 0.f, 0.f, 0.f};

  for (int kt = 0; kt < cE / 64; ++kt) {
    float4 av[8], bv[8];
    const float* ap = arow + kt * 64;
    const float* bp = brow + kt * 64;
#pragma unroll
    for (int q = 0; q < 8; ++q) {
      av[q] = *(const float4*)(ap + 4 * q);
      bv[q] = *(const float4*)(bp + 4 * q);
    }
    unsigned int pa[16], pb[16];
#pragma unroll
    for (int q = 0; q < 8; ++q) {
      pa[2*q]   = pack2bf(av[q].x, av[q].y);
      pa[2*q+1] = pack2bf(av[q].z, av[q].w);
      pb[2*q]   = pack2bf(bv[q].x, bv[q].y);
      pb[2*q+1] = pack2bf(bv[q].z, bv[q].w);
    }
    __syncthreads();   // prior mfma reads done before overwrite
#pragma unroll
    for (int q = 0; q < 4; ++q) {
      *(uint4*)(adst + q * 8) = make_uint4(pa[4*q], pa[4*q+1], pa[4*q+2], pa[4*q+3]);
      *(uint4*)(bdst + q * 8) = make_uint4(pb[4*q], pb[4*q+1], pb[4*q+2], pb[4*q+3]);
    }
    __syncthreads();
#pragma unroll
    for (int ks = 0; ks < 2; ++ks) {
      bf16x8 aF[4], bF[4];
#pragma unroll
      for (int i = 0; i < 4; ++i)
        aF[i] = *(const bf16x8*)(&Al[ks * SLAB + (wm * 64 + i * 16 + fr) * RS + fq * 8]);
#pragma unroll
      for (int j = 0; j < 4; ++j)
        bF[j] = *(const bf16x8*)(&Bl[ks * SLAB + (wn * 64 + j * 16 + fr) * RS + fq * 8]);
#pragma unroll
      for (int i = 0; i < 4; ++i)
#pragma unroll
        for (int j = 0; j < 4; ++j)
          acc[i][j] = __builtin_amdgcn_mfma_f32_16x16x32_bf16(aF[i], bF[j], acc[i][j], 0, 0, 0);
    }
  }

#pragma unroll
  for (int i = 0; i < 4; ++i)
#pragma unroll
    for (int j = 0; j < 4; ++j) {
      const int gcol = wn * 64 + j * 16 + fr;
#pragma unroll
      for (int r = 0; r < 4; ++r) {
        const int grow = m0 + wm * 64 + i * 16 + fq * 4 + r;
        P[(size_t)grow * cNG + n0 + gcol] = f2bf(acc[i][j][r] + bias_s[gcol]);
      }
    }
}

// ---------------------------------------------------------------------------
// LSTM step, both directions: one wave per block, 256 blocks.
// Block = (d, b-tile of 32, j-tile of 16 spanning all 4 gates).
// A (h bf16) and B (W bf16) fragments loaded straight from global (L2-hot):
// no LDS, no syncthreads. Gate fusion in-lane: acc col = j, 4 gate accs.
// ---------------------------------------------------------------------------
__global__ __launch_bounds__(64) void k_lstm_mfma(
    int t_f, int t_b,
    const unsigned short* __restrict__ hin,   // [2][256][256] bf16
    unsigned short* __restrict__ hout,        // [2][256][256] bf16
    float* __restrict__ cbuf,                 // [2][256][256] f32 (in-place)
    const unsigned short* __restrict__ Wbf,   // [2][1024][256] bf16
    const __hip_bfloat16* __restrict__ Pf,
    const __hip_bfloat16* __restrict__ Pb,
    float* __restrict__ feats)
{
  const int bid = blockIdx.x;
  const int d   = bid >> 7;
  const int rr  = bid & 127;
  const int b0  = (rr & 7) * 32;
  const int j0  = (rr >> 3) * 16;
  const int t   = d ? t_b : t_f;
  const __hip_bfloat16* P = d ? Pb : Pf;

  const int lane = threadIdx.x;
  const int fr = lane & 15, fq = lane >> 4;

  const unsigned short* hbase = hin + d * (cB * cHD);
  const unsigned short* wbase = Wbf + d * (cNG * cHD);

  f32x4 acc[2][4];
#pragma unroll
  for (int mf = 0; mf < 2; ++mf)
#pragma unroll
    for (int g = 0; g < 4; ++g) acc[mf][g] = (f32x4){0.f, 0.f, 0.f, 0.f};

#pragma unroll
  for (int k0 = 0; k0 < 8; ++k0) {
    const int kof = k0 * 32 + fq * 8;
    const bf16x8 a0 = *(const bf16x8*)(hbase + (b0 + fr) * cHD + kof);
    const bf16x8 a1 = *(const bf16x8*)(hbase + (b0 + 16 + fr) * cHD + kof);
    bf16x8 bg[4];
#pragma unroll
    for (int g = 0; g < 4; ++g)
      bg[g] = *(const bf16x8*)(wbase + (g * cHD + j0 + fr) * cHD + kof);
#pragma unroll
    for (int g = 0; g < 4; ++g) {
      acc[0][g] = __builtin_amdgcn_mfma_f32_16x16x32_bf16(a0, bg[g], acc[0][g], 0, 0, 0);
      acc[1][g] = __builtin_amdgcn_mfma_f32_16x16x32_bf16(a1, bg[g], acc[1][g], 0, 0, 0);
    }
  }

  const int jj = j0 + fr;             // gate-local column 0..255
  const unsigned short* Pu = (const unsigned short*)P;
#pragma unroll
  for (int mf = 0; mf < 2; ++mf) {
#pragma unroll
    for (int r = 0; r < 4; ++r) {
      const int b = b0 + mf * 16 + fq * 4 + r;
      const size_t prow = ((size_t)t * cB + b) * cNG;
      const float zi = acc[mf][0][r] + bf2f(Pu[prow + 0 * cHD + jj]);
      const float zf = acc[mf][1][r] + bf2f(Pu[prow + 1 * cHD + jj]);
      const float zg = acc[mf][2][r] + bf2f(Pu[prow + 2 * cHD + jj]);
      const float zo = acc[mf][3][r] + bf2f(Pu[prow + 3 * cHD + jj]);
      const int cidx = d * (cB * cHD) + b * cHD + jj;
      const float cold = cbuf[cidx];
      const float cn = fsig(zf) * cold + fsig(zi) * ftanh_(zg);
      cbuf[cidx] = cn;
      const float h = fsig(zo) * ftanh_(cn);
      hout[cidx] = f2bf(h);
      feats[((size_t)t * cB + b) * cH + d * cHD + jj] = h;
    }
  }
}

// ---------------------------------------------------------------------------
// GEMM 3: em[m][n] = sum_k feats[m][k] * W_out[n][k] + b_out[n]  (f32 out)
// ---------------------------------------------------------------------------
__global__ __launch_bounds__(256) void k_em_gemm(
    const float* __restrict__ A, const float* __restrict__ W,
    const float* __restrict__ bias, float* __restrict__ C)
{
  __shared__ float As[16][68];
  __shared__ float Bs[16][68];
  const int tid = threadIdx.x;
  const int tx = tid & 15, ty = tid >> 4;
  const int m0 = blockIdx.y * 64, n0 = blockIdx.x * 64;
  const int lm = tid >> 2;
  const int lk = (tid & 3) * 4;
  const float* arow = A + (size_t)(m0 + lm) * cH;
  const int nrow = n0 + lm;
  const bool bval = nrow < cT;
  const float* brow = W + (size_t)(bval ? nrow : 0) * cH;
  float acc[4][4] = {};
  for (int k0 = 0; k0 < cH; k0 += 16) {
    const float4 av = *(const float4*)(arow + k0 + lk);
    float4 bv = make_float4(0.f,0.f,0.f,0.f);
    if (bval) bv = *(const float4*)(brow + k0 + lk);
    __syncthreads();
    As[lk+0][lm]=av.x; As[lk+1][lm]=av.y; As[lk+2][lm]=av.z; As[lk+3][lm]=av.w;
    Bs[lk+0][lm]=bv.x; Bs[lk+1][lm]=bv.y; Bs[lk+2][lm]=bv.z; Bs[lk+3][lm]=bv.w;
    __syncthreads();
#pragma unroll
    for (int kk = 0; kk < 16; ++kk) {
      const float4 a4 = *(const float4*)(&As[kk][ty*4]);
      const float4 b4 = *(const float4*)(&Bs[kk][tx*4]);
      const float a[4] = {a4.x,a4.y,a4.z,a4.w};
      const float b[4] = {b4.x,b4.y,b4.z,b4.w};
#pragma unroll
      for (int i=0;i<4;++i)
#pragma unroll
        for (int j=0;j<4;++j) acc[i][j] += a[i]*b[j];
    }
  }
#pragma unroll
  for (int i=0;i<4;++i) {
    const int mrow = m0 + ty*4 + i;
#pragma unroll
    for (int j=0;j<4;++j) {
      const int n = n0 + tx*4 + j;
      if (n < cT) C[(size_t)mrow * cT + n] = acc[i][j] + bias[n];
    }
  }
}

// ---------------------------------------------------------------------------
// CRF: one block per batch element, 320 threads (5 waves). (unchanged)
// ---------------------------------------------------------------------------
__global__ __launch_bounds__(320) void k_crf(
    const float* __restrict__ em,       // (S,B,T)
    const int* __restrict__ tag_ids,    // (B,S)
    const int* __restrict__ lengths,    // (B,)
    const float* __restrict__ start_trans,
    const float* __restrict__ end_trans,
    const float* __restrict__ trans,    // (T,T)
    float* __restrict__ llh)            // (B,)
{
  const int b = blockIdx.x;
  const int tid = threadIdx.x;
  const int len = lengths[b];

  __shared__ float trans_t[80 * 81];    // [j][i], stride 81
  __shared__ float em_s[cS * 80];       // [t][j], stride 80
  __shared__ float a0[80], a1[80];
  __shared__ float red[128];
  __shared__ float score_sh;

  for (int idx = tid; idx < cT * cT; idx += 320) {
    const int i = idx / cT, jj = idx - i * cT;
    trans_t[jj * 81 + i] = trans[idx];
  }
  for (int idx = tid; idx < cS * cT; idx += 320) {
    const int t = idx / cT, jj = idx - t * cT;
    em_s[t * 80 + jj] = em[((size_t)t * cB + b) * cT + jj];
  }
  __syncthreads();

  float contrib = 0.f;
  if (tid < cS) {
    const int t = tid;
    if (t == 0) {
      const int tg = tag_ids[b * cS];
      contrib = start_trans[tg] + em_s[tg];
    } else if (t < len) {
      const int tg = tag_ids[b * cS + t];
      const int tp = tag_ids[b * cS + t - 1];
      contrib = trans_t[tg * 81 + tp] + em_s[t * 80 + tg];
    }
    if (t == len - 1) contrib += end_trans[tag_ids[b * cS + len - 1]];
  }
  if (tid < 128) red[tid] = contrib;
  __syncthreads();
  for (int s = 64; s > 0; s >>= 1) {
    if (tid < s) red[tid] += red[tid + s];
    __syncthreads();
  }
  if (tid == 0) score_sh = red[0];

  const int j   = tid >> 2;
  const int sub = tid & 3;
  const int i0  = sub * 19;
  float* cur = a0;
  float* nxt = a1;
  if (sub == 0 && j < cT) cur[j] = start_trans[j] + em_s[j];
  __syncthreads();
  for (int t = 1; t < len; ++t) {
    const float mref = cur[0];
    const float* trow = &trans_t[j * 81 + i0];
    const float* crow = &cur[i0];
    float s = 0.f;
#pragma unroll
    for (int q = 0; q < 19; ++q)
      s += __expf(crow[q] + trow[q] - mref);
    s += __shfl_xor(s, 1);
    s += __shfl_xor(s, 2);
    if (sub == 0 && j < cT) nxt[j] = mref + __logf(s) + em_s[t * 80 + j];
    __syncthreads();
    float* tp2 = cur; cur = nxt; nxt = tp2;
  }

  const float v = (tid < cT) ? cur[tid] + end_trans[tid] : -1e30f;
  if (tid < 128) red[tid] = v;
  __syncthreads();
  for (int s = 64; s > 0; s >>= 1) {
    if (tid < s) red[tid] = fmaxf(red[tid], red[tid + s]);
    __syncthreads();
  }
  const float mx = red[0];
  __syncthreads();
  if (tid < 128) red[tid] = (tid < cT) ? __expf(v - mx) : 0.f;
  __syncthreads();
  for (int s = 64; s > 0; s >>= 1) {
    if (tid < s) red[tid] += red[tid + s];
    __syncthreads();
  }
  if (tid == 0) llh[b] = score_sh - (mx + __logf(red[0]));
}

__global__ __launch_bounds__(256) void k_final(const float* __restrict__ llh,
                                               float* __restrict__ out)
{
  __shared__ float red[256];
  const int tid = threadIdx.x;
  red[tid] = llh[tid];
  __syncthreads();
  for (int s = 128; s > 0; s >>= 1) {
    if (tid < s) red[tid] += red[tid + s];
    __syncthreads();
  }
  if (tid == 0) out[0] = -red[0] * (1.0f / cB);
}

} // anonymous namespace

extern "C" void kernel_launch(void* const* d_in, const int* in_sizes, int n_in,
                              void* d_out, int out_size, void* d_ws, size_t ws_size,
                              hipStream_t stream) {
  const int*   input_ids   = (const int*)  d_in[0];
  const int*   tag_ids     = (const int*)  d_in[1];
  const int*   lengths     = (const int*)  d_in[2];
  const float* embed_table = (const float*)d_in[3];
  const float* W_ih_f      = (const float*)d_in[4];
  const float* W_hh_f      = (const float*)d_in[5];
  const float* b_ih_f      = (const float*)d_in[6];
  const float* b_hh_f      = (const float*)d_in[7];
  const float* W_ih_b      = (const float*)d_in[8];
  const float* W_hh_b      = (const float*)d_in[9];
  const float* b_ih_b      = (const float*)d_in[10];
  const float* b_hh_b      = (const float*)d_in[11];
  const float* W_out       = (const float*)d_in[12];
  const float* b_out       = (const float*)d_in[13];
  const float* start_trans = (const float*)d_in[14];
  const float* end_trans   = (const float*)d_in[15];
  const float* trans       = (const float*)d_in[16];
  const float* h0          = (const float*)d_in[17];
  const float* c0          = (const float*)d_in[18];
  float* out = (float*)d_out;

  // workspace layout
  char* wsb = (char*)d_ws;
  const size_t szP     = (size_t)cM * cNG * sizeof(__hip_bfloat16); // 64 MiB
  const size_t szFeats = (size_t)cM * cH * sizeof(float);           // 64 MiB
  const size_t szEm    = (size_t)cM * cT * sizeof(float);
  const size_t szWbf   = (size_t)2 * cNG * cHD * sizeof(unsigned short); // 1 MiB
  const size_t szHbuf  = (size_t)2 * cB * cHD * sizeof(unsigned short);  // 256 KiB
  const size_t szCbuf  = (size_t)2 * cB * cHD * sizeof(float);           // 512 KiB
  __hip_bfloat16* Pf = (__hip_bfloat16*)(wsb);
  __hip_bfloat16* Pb = (__hip_bfloat16*)(wsb + szP);
  float* feats = (float*)(wsb + 2*szP);
  float* em    = (float*)(wsb + 2*szP + szFeats);
  unsigned short* Wbf = (unsigned short*)(wsb + 2*szP + szFeats + szEm);
  unsigned short* hA  = (unsigned short*)(wsb + 2*szP + szFeats + szEm + szWbf);
  unsigned short* hB  = (unsigned short*)(wsb + 2*szP + szFeats + szEm + szWbf + szHbuf);
  float* cbuf  = (float*)(wsb + 2*szP + szFeats + szEm + szWbf + 2*szHbuf);
  float* llh   = (float*)(wsb + 2*szP + szFeats + szEm + szWbf + 2*szHbuf + szCbuf);

  // 0) prep: W_hh -> bf16, h0 -> bf16 ping, c0 -> f32 working copy
  k_prep<<<2048, 256, 0, stream>>>(W_hh_f, W_hh_b, h0, c0, Wbf, hA, cbuf);

  // 1) input projections, both directions, bf16 MFMA (XCD-remapped 1D grid)
  k_embed_mfma<<<4096, 256, 0, stream>>>(input_ids, embed_table,
                                         W_ih_f, W_ih_b,
                                         b_ih_f, b_hh_f, b_ih_b, b_hh_b,
                                         Pf, Pb);

  // 2) recurrence: 128 steps, one-wave MFMA blocks, h ping-pong
  for (int tau = 0; tau < cS; ++tau) {
    const unsigned short* hin = (tau & 1) ? hB : hA;
    unsigned short* hout      = (tau & 1) ? hA : hB;
    k_lstm_mfma<<<256, 64, 0, stream>>>(tau, cS - 1 - tau, hin, hout, cbuf,
                                        Wbf, Pf, Pb, feats);
  }

  // 3) emissions
  dim3 g3((cT + 63) / 64, cM / 64);
  k_em_gemm<<<g3, 256, 0, stream>>>(feats, W_out, b_out, em);

  // 4) CRF per batch element + final mean
  k_crf<<<cB, 320, 0, stream>>>(em, tag_ids, lengths, start_trans, end_trans, trans, llh);
  k_final<<<1, 256, 0, stream>>>(llh, out);
}